// Round 24
// baseline (133.684 us; speedup 1.0000x reference)
//
#include <hip/hip_runtime.h>

using f16   = _Float16;
using f16x2 = __attribute__((ext_vector_type(2))) f16;
using f16x4 = __attribute__((ext_vector_type(4))) f16;
using f16x8 = __attribute__((ext_vector_type(8))) f16;
using f32x4 = __attribute__((ext_vector_type(4))) float;

#define L_ 4096
#define C_ 512

static __device__ __forceinline__ float fast_exp2(float x) {
#if __has_builtin(__builtin_amdgcn_exp2f)
  return __builtin_amdgcn_exp2f(x);
#else
  float r; asm("v_exp_f32 %0, %1" : "=v"(r) : "v"(x)); return r;
#endif
}

// packed f32->f16 (RTZ) convert; bit-cast __fp16 vec -> _Float16 vec
static __device__ __forceinline__ f16x2 pk2(float a, float b) {
  return __builtin_bit_cast(f16x2, __builtin_amdgcn_cvt_pkrtz(a, b));
}

// async 16B global -> LDS DMA (linear dest; source carries the swizzle)
static __device__ __forceinline__ void gl16(const char* g, char* l) {
  __builtin_amdgcn_global_load_lds(
      (const __attribute__((address_space(1))) unsigned int*)g,
      (__attribute__((address_space(3))) unsigned int*)l, 16, 0, 0);
}

// workspace layout (bytes), all offsets 256-aligned
#define WS_SC    0u          // float2[4096*16]   sin/cos table      524288
#define WS_WQKV  524288u     // f16[768*512]                         786432
#define WS_WO    1310720u    // f16[512*512]                         524288
#define WS_Q     1835008u    // f16[2][8][4096][64]                  8388608
#define WS_K     10223616u   // f16[2][2][64][64][64] chunked K      2097152
#define WS_VT    12320768u   // f16[2][2][64][64][64] chunked V      2097152
#define WS_ATT   14417920u   // f16[2][4096][512]  (SPLIT=1 path)    8388608
#define WS_OP    22806528u   // f16[2][2][8][4096][64] O partials    16777216
#define WS_LS2   56360960u   // f32[4][8][4096]  lsum partials       524288
#define WS_END2  56885248u

// ---------------------------------------------------------------- prep
__global__ __launch_bounds__(256) void prep_kernel(
    const float* __restrict__ Wq, const float* __restrict__ Wkv,
    const float* __restrict__ Wo,
    f16* __restrict__ wqkv, f16* __restrict__ wo16, float2* __restrict__ sc) {
  int t = blockIdx.x * 256 + threadIdx.x;
  if (t < 98304) {                 // 768*512 f16, 4 per thread
    int idx = t * 4;
    float4 v = (idx < 262144) ? *(const float4*)(Wq + idx)
                              : *(const float4*)(Wkv + (idx - 262144));
    f16x4 o = {(f16)v.x, (f16)v.y, (f16)v.z, (f16)v.w};
    *(f16x4*)(wqkv + idx) = o;
  } else if (t < 163840) {         // 512*512 f16
    int idx = (t - 98304) * 4;
    float4 v = *(const float4*)(Wo + idx);
    f16x4 o = {(f16)v.x, (f16)v.y, (f16)v.z, (f16)v.w};
    *(f16x4*)(wo16 + idx) = o;
  } else if (t < 229376) {         // 4096*16 sin/cos entries
    int e = t - 163840;
    int l = e >> 4, p = e & 15;
    float invf = exp2f(-(float)p * (13.287712379549449f / 16.0f));
    float ang = (float)l * invf;
    sc[e] = make_float2(sinf(ang), cosf(ang));
  }
}

// ---------------------------------------------------------------- QKV + RoPE
// x panel (512c x 32l) staged ONCE into a 32KB LDS tile, transposed to [l][c]
// f16 with 16B-unit XOR swizzle (unit ^= l&7). B-fragment = one ds_read_b128.
// K/V outputs stored chunked+swizzled for attn's global_load_lds.
__global__ __launch_bounds__(256) void qkv_kernel(
    const float* __restrict__ x, const f16* __restrict__ wqkv,
    const float2* __restrict__ sc,
    f16* __restrict__ Qo, f16* __restrict__ Ko, f16* __restrict__ Vto) {
  __shared__ __align__(16) f16 xt[32 * 512];     // [l][c], swizzled
  char* xl = (char*)xt;
  int bid = blockIdx.x;
  int b   = bid / 384;
  int rem = bid % 384;
  int ot  = rem >> 7;       // 0..2
  int lt  = rem & 127;      // 0..127
  int wave = threadIdx.x >> 6, lane = threadIdx.x & 63;
  int lo = lane & 15, hi = lane >> 4;
  int obase = ot * 256 + wave * 64;
  int lbase = lt * 32;
  const float* xb = x + (size_t)b * C_ * L_;

  {
    int l  = threadIdx.x & 31;
    int cg = threadIdx.x >> 5;         // 0..7
#pragma unroll
    for (int p = 0; p < 16; ++p) {
      int c4 = (p * 8 + cg) * 4;
      float v0 = xb[(size_t)(c4 + 0) * L_ + lbase + l];
      float v1 = xb[(size_t)(c4 + 1) * L_ + lbase + l];
      float v2 = xb[(size_t)(c4 + 2) * L_ + lbase + l];
      float v3 = xb[(size_t)(c4 + 3) * L_ + lbase + l];
      f16x2 p01 = pk2(v0, v1), p23 = pk2(v2, v3);
      f16x4 w = {p01[0], p01[1], p23[0], p23[1]};
      int col = (c4 * 2) ^ ((l & 7) * 16);
      *(f16x4*)(xl + l * 1024 + col) = w;
    }
  }
  __syncthreads();

  f32x4 acc[4][2] = {};
  for (int kc = 0; kc < 512; kc += 32) {
    f16x8 aw[4];
#pragma unroll
    for (int oc = 0; oc < 4; ++oc)
      aw[oc] = *(const f16x8*)(wqkv + (obase + oc * 16 + lo) * 512 + kc + hi * 8);
#pragma unroll
    for (int lc = 0; lc < 2; ++lc) {
      int row = lc * 16 + lo;
      f16x8 bx = *(const f16x8*)(xl + row * 1024 + (((kc + hi * 8) * 2) ^ ((row & 7) * 16)));
#pragma unroll
      for (int oc = 0; oc < 4; ++oc)
        acc[oc][lc] = __builtin_amdgcn_mfma_f32_16x16x32_f16(aw[oc], bx, acc[oc][lc], 0, 0, 0);
    }
  }

  bool is_q = obase < 512;
  int  og   = obase - 512;
  int  kvh  = is_q ? 0 : (og >> 7);
  bool is_v = (!is_q) && ((og & 127) == 64);
  int  h    = obase >> 6;
  const float QSCALE = 0.125f * 1.44269504088896340736f;

#pragma unroll
  for (int oc = 0; oc < 4; ++oc) {
#pragma unroll
    for (int lc = 0; lc < 2; ++lc) {
      f32x4 v = acc[oc][lc];
      int l = lbase + lc * 16 + lo;
      int d = oc * 16 + hi * 4;
      if (!is_v && oc < 2) {           // rotary on d<32 for q and k
        int p0 = d >> 1;
        float2 s0 = sc[l * 16 + p0];
        float2 s1 = sc[l * 16 + p0 + 1];
        float a0 = v[0], a1 = v[1], a2 = v[2], a3 = v[3];
        v[0] = a0 * s0.y - a1 * s0.x;
        v[1] = a1 * s0.y + a0 * s0.x;
        v[2] = a2 * s1.y - a3 * s1.x;
        v[3] = a3 * s1.y + a2 * s1.x;
      }
      if (is_q) {
        f16x4 st = {(f16)(v[0] * QSCALE), (f16)(v[1] * QSCALE),
                    (f16)(v[2] * QSCALE), (f16)(v[3] * QSCALE)};
        *(f16x4*)(Qo + (((size_t)b * 8 + h) * L_ + l) * 64 + d) = st;
      } else if (!is_v) {
        f16x4 st = {(f16)v[0], (f16)v[1], (f16)v[2], (f16)v[3]};
        int t = l >> 6, r = l & 63;
        int u = (d >> 3) ^ (r & 7);
        int w = (hi & 1) * 8;
        char* Kb = (char*)Ko + (size_t)(b * 2 + kvh) * (L_ * 128);
        *(f16x4*)(Kb + (size_t)t * 8192 + r * 128 + u * 16 + w) = st;
      } else {
        int t = l >> 6, kk = l & 63;
        int m = kk >> 3, i8 = kk & 7;
        int ca = (m >> 2) * 64 + ((2 * m) & 3) * 16 + ((m >> 1) & 1) * 8;
        int bcol = ca + (i8 < 4 ? 2 * i8 : 8 + 2 * i8);
        char* Vb = (char*)Vto + (size_t)(b * 2 + kvh) * (L_ * 128);
#pragma unroll
        for (int i = 0; i < 4; ++i) {
          int rv = d + i;
          *(f16*)(Vb + (size_t)t * 8192 + rv * 128 + (bcol ^ ((rv & 7) << 4))) = (f16)v[i];
        }
      }
    }
  }
}

// ---------------------------------------------------------------- flash attention
// Block = 8 waves x 64 q rows = 512 q rows, 512 threads. qi=4. SPLIT=2.
// 8 LDS buffers (128 KB; 1 block/CU so LDS is free), ONE barrier per 4 chunks:
// per iteration, STAGE chunks t+4..t+7 (DMA latency hides under the 4
// COMPUTEs), run 4 COMPUTEs, then a single vmcnt-drain + barrier. Fewer
// barrier drains + waves drift across chunks -> staggered MFMA/VALU phases.
template <int SPLIT>
__global__ __launch_bounds__(512) void attn_kernel(
    const f16* __restrict__ Qi, const f16* __restrict__ Ki,
    const f16* __restrict__ Vti, f16* __restrict__ att,
    f16* __restrict__ opart, float* __restrict__ lsews) {
  __shared__ __align__(16) char smem[8][16384];
  int bid  = blockIdx.x;
  int half = (SPLIT > 1) ? (bid >> 7) : 0;
  int rem7 = bid & 127;
  int b   = rem7 >> 6;
  int rr  = rem7 & 63;
  int h   = rr >> 3;
  int qt  = rr & 7;
  int tid  = threadIdx.x;
  int wave = tid >> 6, lane = tid & 63;
  int lo = lane & 15, hi = lane >> 4;
  int kvh = h >> 2;
  const f16*  Qp   = Qi + ((size_t)(b * 8 + h) * L_) * 64;
  const char* Ksrc = (const char*)Ki  + (size_t)(b * 2 + kvh) * (L_ * 128)
                     + (size_t)half * (L_ / SPLIT) * 128;
  const char* Vsrc = (const char*)Vti + (size_t)(b * 2 + kvh) * (L_ * 128)
                     + (size_t)half * (L_ / SPLIT) * 128;

  int lqb = qt * 512 + wave * 64;
  f16x8 qf[4][2];
#pragma unroll
  for (int qi = 0; qi < 4; ++qi)
#pragma unroll
    for (int hf = 0; hf < 2; ++hf)
      qf[qi][hf] = *(const f16x8*)(Qp + (size_t)(lqb + qi * 16 + lo) * 64 + hf * 32 + hi * 8);

  int c0 = tid;                      // 512 threads x 16B = 8KB tile
#define STAGE(t, base_) do {                                           \
    gl16(Ksrc + (size_t)(t) * 8192 + c0 * 16, (char*)(base_) + c0 * 16); \
    gl16(Vsrc + (size_t)(t) * 8192 + c0 * 16, (char*)(base_) + 8192 + c0 * 16); \
  } while (0)

  f32x4 oacc[4][4] = {};
  f32x4 lse[4] = {};
  const f16x8 ones8 = {(f16)1.f, (f16)1.f, (f16)1.f, (f16)1.f,
                       (f16)1.f, (f16)1.f, (f16)1.f, (f16)1.f};
  int swz = (lo & 7) << 4;

#define COMPUTE(buf_) do {                                                          \
    const char* kb = (const char*)(buf_);                                           \
    const char* vb = kb + 8192;                                                     \
    _Pragma("unroll")                                                               \
    for (int jp = 0; jp < 2; ++jp) {                                                \
      f32x4 s[2][4] = {};                                                           \
      __builtin_amdgcn_s_setprio(1);                                                \
      _Pragma("unroll")                                                             \
      for (int jj = 0; jj < 2; ++jj) {                                              \
        int j = jp * 2 + jj;                                                        \
        f16x8 ka0 = *(const f16x8*)(kb + (j * 16 + lo) * 128 + ((hi * 16) ^ swz));  \
        f16x8 ka1 = *(const f16x8*)(kb + (j * 16 + lo) * 128 + ((64 + hi * 16) ^ swz)); \
        _Pragma("unroll")                                                           \
        for (int qi = 0; qi < 4; ++qi) {                                            \
          s[jj][qi] = __builtin_amdgcn_mfma_f32_16x16x32_f16(ka0, qf[qi][0], s[jj][qi], 0, 0, 0); \
          s[jj][qi] = __builtin_amdgcn_mfma_f32_16x16x32_f16(ka1, qf[qi][1], s[jj][qi], 0, 0, 0); \
        }                                                                           \
      }                                                                             \
      __builtin_amdgcn_s_setprio(0);                                                \
      f16x8 pc[4];                                                                  \
      _Pragma("unroll")                                                             \
      for (int qi = 0; qi < 4; ++qi) {                                              \
        f16x2 a0 = pk2(fast_exp2(s[0][qi][0]), fast_exp2(s[0][qi][1]));             \
        f16x2 a1 = pk2(fast_exp2(s[0][qi][2]), fast_exp2(s[0][qi][3]));             \
        f16x2 b0 = pk2(fast_exp2(s[1][qi][0]), fast_exp2(s[1][qi][1]));             \
        f16x2 b1 = pk2(fast_exp2(s[1][qi][2]), fast_exp2(s[1][qi][3]));             \
        f16x4 l4 = __builtin_shufflevector(a0, a1, 0, 1, 2, 3);                     \
        f16x4 h4 = __builtin_shufflevector(b0, b1, 0, 1, 2, 3);                     \
        pc[qi] = __builtin_shufflevector(l4, h4, 0, 1, 2, 3, 4, 5, 6, 7);           \
      }                                                                             \
      __builtin_amdgcn_s_setprio(1);                                                \
      _Pragma("unroll")                                                             \
      for (int dc = 0; dc < 4; ++dc) {                                              \
        f16x8 vv = *(const f16x8*)(vb + (dc * 16 + lo) * 128 + ((jp * 64 + hi * 16) ^ swz)); \
        _Pragma("unroll")                                                           \
        for (int qi = 0; qi < 4; ++qi)                                              \
          oacc[dc][qi] = __builtin_amdgcn_mfma_f32_16x16x32_f16(vv, pc[qi], oacc[dc][qi], 0, 0, 0); \
      }                                                                             \
      _Pragma("unroll")                                                             \
      for (int qi = 0; qi < 4; ++qi)                                                \
        lse[qi] = __builtin_amdgcn_mfma_f32_16x16x32_f16(ones8, pc[qi], lse[qi], 0, 0, 0); \
      __builtin_amdgcn_s_setprio(0);                                                \
    }                                                                               \
  } while (0)

  const int NT = 64 / SPLIT;            // 32 (SPLIT=2) or 64 (SPLIT=1); %4 == 0
#pragma unroll
  for (int p = 0; p < 4; ++p) STAGE(p, smem[p]);
  __syncthreads();

  for (int t = 0; t < NT; t += 4) {
#pragma unroll
    for (int k = 0; k < 4; ++k)
      if (t + 4 + k < NT) STAGE(t + 4 + k, smem[(t + 4 + k) & 7]);
#pragma unroll
    for (int k = 0; k < 4; ++k)
      COMPUTE(smem[(t + k) & 7]);
    __syncthreads();
  }

#pragma unroll
  for (int qi = 0; qi < 4; ++qi) {
    int lq = lqb + qi * 16 + lo;
    if constexpr (SPLIT > 1) {
      size_t obase = (((size_t)(half * 2 + b) * 8 + h) * L_ + lq) * 64;
#pragma unroll
      for (int dc = 0; dc < 4; ++dc) {
        f16x4 st;
#pragma unroll
        for (int i = 0; i < 4; ++i) st[i] = (f16)oacc[dc][qi][i];
        *(f16x4*)(opart + obase + dc * 16 + hi * 4) = st;
      }
      if (hi == 0)
        lsews[((size_t)(half * 2 + b) * 8 + h) * L_ + lq] = lse[qi][0];
    } else {
      float inv = 1.f / lse[qi][0];
#pragma unroll
      for (int dc = 0; dc < 4; ++dc) {
        f16x4 st;
#pragma unroll
        for (int i = 0; i < 4; ++i) st[i] = (f16)(oacc[dc][qi][i] * inv);
        *(f16x4*)(att + ((size_t)b * L_ + lq) * 512 + h * 64 + dc * 16 + hi * 4) = st;
      }
    }
  }
#undef STAGE
#undef COMPUTE
}

// ---------------------------------------------------------------- fused combine + output projection (v2)
__global__ __launch_bounds__(256) void oproj_fused_kernel(
    const f16* __restrict__ opart, const float* __restrict__ lsews,
    const f16* __restrict__ wo16, float* __restrict__ out) {
  __shared__ __align__(16) f16 bt[32 * 512];     // [l][o], swizzled
  __shared__ float linv[32][8];
  char* bl = (char*)bt;
  int bid = blockIdx.x;
  int b   = bid >> 7;
  int lt  = bid & 127;
  int lbase = lt * 32;
  int tid  = threadIdx.x;
  int wave = tid >> 6, lane = tid & 63;
  int lo = lane & 15, hi = lane >> 4;
  const size_t HS  = (size_t)2 * 8 * 4096 * 64;   // opart half stride (f16 elems)
  const size_t LSS = (size_t)2 * 8 * 4096;        // lsews half stride

  {
    int r = tid >> 3, h = tid & 7;
    size_t lidx = ((size_t)b * 8 + h) * L_ + lbase + r;
    linv[r][h] = 1.f / (lsews[lidx] + lsews[LSS + lidx]);
  }
  __syncthreads();

#pragma unroll
  for (int p = 0; p < 8; ++p) {
    int idx = p * 256 + tid;
    int r = idx >> 6, u = idx & 63;
    int h = u >> 3, d = (u & 7) * 8;
    size_t base = (((size_t)b * 8 + h) * L_ + lbase + r) * 64 + d;
    f16x8 p0 = *(const f16x8*)(opart + base);
    f16x8 p1 = *(const f16x8*)(opart + HS + base);
    float iv = linv[r][h];
    f16x2 c0 = pk2(((float)p0[0] + (float)p1[0]) * iv, ((float)p0[1] + (float)p1[1]) * iv);
    f16x2 c1 = pk2(((float)p0[2] + (float)p1[2]) * iv, ((float)p0[3] + (float)p1[3]) * iv);
    f16x2 c2 = pk2(((float)p0[4] + (float)p1[4]) * iv, ((float)p0[5] + (float)p1[5]) * iv);
    f16x2 c3 = pk2(((float)p0[6] + (float)p1[6]) * iv, ((float)p0[7] + (float)p1[7]) * iv);
    f16x8 w = {c0[0], c0[1], c1[0], c1[1], c2[0], c2[1], c3[0], c3[1]};
    *(f16x8*)(bl + r * 1024 + ((u * 16) ^ ((r & 7) * 16))) = w;
  }
  __syncthreads();

  float* ob = out + (size_t)b * C_ * L_;
#pragma unroll
  for (int ct = 0; ct < 2; ++ct) {
    int cobase = ct * 256 + wave * 64;
    f32x4 acc[4][2] = {};
    for (int kc = 0; kc < 512; kc += 32) {
      f16x8 aw[4];
#pragma unroll
      for (int cc = 0; cc < 4; ++cc)
        aw[cc] = *(const f16x8*)(wo16 + (cobase + cc * 16 + lo) * 512 + kc + hi * 8);
#pragma unroll
      for (int lc = 0; lc < 2; ++lc) {
        int row = lc * 16 + lo;
        f16x8 bx = *(const f16x8*)(bl + row * 1024 + (((kc + hi * 8) * 2) ^ ((row & 7) * 16)));
#pragma unroll
        for (int cc = 0; cc < 4; ++cc)
          acc[cc][lc] = __builtin_amdgcn_mfma_f32_16x16x32_f16(aw[cc], bx, acc[cc][lc], 0, 0, 0);
      }
    }
#pragma unroll
    for (int cc = 0; cc < 4; ++cc)
#pragma unroll
      for (int lc = 0; lc < 2; ++lc) {
        int l = lbase + lc * 16 + lo;
#pragma unroll
        for (int i = 0; i < 4; ++i) {
          int co = cobase + cc * 16 + hi * 4 + i;
          ob[(size_t)co * L_ + l] = acc[cc][lc][i];
        }
      }
  }
}

// ---------------------------------------------------------------- output projection (SPLIT=1 fallback)
__global__ __launch_bounds__(256) void oproj_kernel(
    const f16* __restrict__ att, const f16* __restrict__ wo16,
    float* __restrict__ out) {
  int bid = blockIdx.x;
  int b   = bid / 256;
  int rem = bid % 256;
  int ct  = rem >> 7;
  int lt  = rem & 127;
  int wave = threadIdx.x >> 6, lane = threadIdx.x & 63;
  int lo = lane & 15, hi = lane >> 4;
  int cobase = ct * 256 + wave * 64;
  int lbase  = lt * 32;
  const f16* ab = att + (size_t)b * L_ * 512;

  f32x4 acc[4][2] = {};
  for (int kc = 0; kc < 512; kc += 32) {
    f16x8 aw[4];
#pragma unroll
    for (int cc = 0; cc < 4; ++cc)
      aw[cc] = *(const f16x8*)(wo16 + (cobase + cc * 16 + lo) * 512 + kc + hi * 8);
#pragma unroll
    for (int lc = 0; lc < 2; ++lc) {
      f16x8 bx = *(const f16x8*)(ab + (size_t)(lbase + lc * 16 + lo) * 512 + kc + hi * 8);
#pragma unroll
      for (int cc = 0; cc < 4; ++cc)
        acc[cc][lc] = __builtin_amdgcn_mfma_f32_16x16x32_f16(aw[cc], bx, acc[cc][lc], 0, 0, 0);
    }
  }
  float* ob = out + (size_t)b * C_ * L_;
#pragma unroll
  for (int cc = 0; cc < 4; ++cc)
#pragma unroll
    for (int lc = 0; lc < 2; ++lc) {
      int l = lbase + lc * 16 + lo;
#pragma unroll
      for (int i = 0; i < 4; ++i) {
        int co = cobase + cc * 16 + hi * 4 + i;
        ob[(size_t)co * L_ + l] = acc[cc][lc][i];
      }
    }
}

// ---------------------------------------------------------------- launch
extern "C" void kernel_launch(void* const* d_in, const int* in_sizes, int n_in,
                              void* d_out, int out_size, void* d_ws, size_t ws_size,
                              hipStream_t stream) {
  const float* x   = (const float*)d_in[0];
  const float* Wq  = (const float*)d_in[1];
  const float* Wkv = (const float*)d_in[2];
  const float* Wo  = (const float*)d_in[3];
  char* ws = (char*)d_ws;
  float2* sc  = (float2*)(ws + WS_SC);
  f16* wqkv   = (f16*)(ws + WS_WQKV);
  f16* wo16   = (f16*)(ws + WS_WO);
  f16* Qb     = (f16*)(ws + WS_Q);
  f16* Kb     = (f16*)(ws + WS_K);
  f16* Vtb    = (f16*)(ws + WS_VT);
  f16* attb   = (f16*)(ws + WS_ATT);
  f16* opb    = (f16*)(ws + WS_OP);
  float* lsb  = (float*)(ws + WS_LS2);

  prep_kernel<<<1024, 256, 0, stream>>>(Wq, Wkv, Wo, wqkv, wo16, sc);
  qkv_kernel<<<768, 256, 0, stream>>>(x, wqkv, sc, Qb, Kb, Vtb);
  if (ws_size >= (size_t)WS_END2) {
    attn_kernel<2><<<256, 512, 0, stream>>>(Qb, Kb, Vtb, attb, opb, lsb);
    oproj_fused_kernel<<<256, 256, 0, stream>>>(opb, lsb, wo16, (float*)d_out);
  } else {
    attn_kernel<1><<<128, 512, 0, stream>>>(Qb, Kb, Vtb, attb, opb, lsb);
    oproj_kernel<<<512, 256, 0, stream>>>(attb, wo16, (float*)d_out);
  }
}

// Round 25
// 131.448 us; speedup vs baseline: 1.0170x; 1.0170x over previous
//
#include <hip/hip_runtime.h>

using f16   = _Float16;
using f16x2 = __attribute__((ext_vector_type(2))) f16;
using f16x4 = __attribute__((ext_vector_type(4))) f16;
using f16x8 = __attribute__((ext_vector_type(8))) f16;
using f32x4 = __attribute__((ext_vector_type(4))) float;

#define L_ 4096
#define C_ 512

static __device__ __forceinline__ float fast_exp2(float x) {
#if __has_builtin(__builtin_amdgcn_exp2f)
  return __builtin_amdgcn_exp2f(x);
#else
  float r; asm("v_exp_f32 %0, %1" : "=v"(r) : "v"(x)); return r;
#endif
}

// packed f32->f16 (RTZ) convert; bit-cast __fp16 vec -> _Float16 vec
static __device__ __forceinline__ f16x2 pk2(float a, float b) {
  return __builtin_bit_cast(f16x2, __builtin_amdgcn_cvt_pkrtz(a, b));
}

// async 16B global -> LDS DMA (linear dest; source carries the swizzle)
static __device__ __forceinline__ void gl16(const char* g, char* l) {
  __builtin_amdgcn_global_load_lds(
      (const __attribute__((address_space(1))) unsigned int*)g,
      (__attribute__((address_space(3))) unsigned int*)l, 16, 0, 0);
}

// workspace layout (bytes), all offsets 256-aligned
#define WS_SC    0u          // float2[4096*16]   sin/cos table      524288
#define WS_WQKV  524288u     // f16[768*512]                         786432
#define WS_WO    1310720u    // f16[512*512]                         524288
#define WS_Q     1835008u    // f16[2][8][4096][64]                  8388608
#define WS_K     10223616u   // f16[2][2][64][64][64] chunked K      2097152
#define WS_VT    12320768u   // f16[2][2][64][64][64] chunked V      2097152
#define WS_ATT   14417920u   // f16[2][4096][512]  (SPLIT=1 path)    8388608
#define WS_OP    22806528u   // f16[2][2][8][4096][64] O partials    16777216
#define WS_LS2   56360960u   // f32[4][8][4096]  lsum partials       524288
#define WS_END2  56885248u

// ---------------------------------------------------------------- prep
__global__ __launch_bounds__(256) void prep_kernel(
    const float* __restrict__ Wq, const float* __restrict__ Wkv,
    const float* __restrict__ Wo,
    f16* __restrict__ wqkv, f16* __restrict__ wo16, float2* __restrict__ sc) {
  int t = blockIdx.x * 256 + threadIdx.x;
  if (t < 98304) {                 // 768*512 f16, 4 per thread
    int idx = t * 4;
    float4 v = (idx < 262144) ? *(const float4*)(Wq + idx)
                              : *(const float4*)(Wkv + (idx - 262144));
    f16x4 o = {(f16)v.x, (f16)v.y, (f16)v.z, (f16)v.w};
    *(f16x4*)(wqkv + idx) = o;
  } else if (t < 163840) {         // 512*512 f16
    int idx = (t - 98304) * 4;
    float4 v = *(const float4*)(Wo + idx);
    f16x4 o = {(f16)v.x, (f16)v.y, (f16)v.z, (f16)v.w};
    *(f16x4*)(wo16 + idx) = o;
  } else if (t < 229376) {         // 4096*16 sin/cos entries
    int e = t - 163840;
    int l = e >> 4, p = e & 15;
    float invf = exp2f(-(float)p * (13.287712379549449f / 16.0f));
    float ang = (float)l * invf;
    sc[e] = make_float2(sinf(ang), cosf(ang));
  }
}

// ---------------------------------------------------------------- QKV + RoPE
// x panel (512c x 32l) staged ONCE into a 32KB LDS tile, transposed to [l][c]
// f16 with 16B-unit XOR swizzle (unit ^= l&7). B-fragment = one ds_read_b128.
// K/V outputs stored chunked+swizzled for attn's global_load_lds.
__global__ __launch_bounds__(256) void qkv_kernel(
    const float* __restrict__ x, const f16* __restrict__ wqkv,
    const float2* __restrict__ sc,
    f16* __restrict__ Qo, f16* __restrict__ Ko, f16* __restrict__ Vto) {
  __shared__ __align__(16) f16 xt[32 * 512];     // [l][c], swizzled
  char* xl = (char*)xt;
  int bid = blockIdx.x;
  int b   = bid / 384;
  int rem = bid % 384;
  int ot  = rem >> 7;       // 0..2
  int lt  = rem & 127;      // 0..127
  int wave = threadIdx.x >> 6, lane = threadIdx.x & 63;
  int lo = lane & 15, hi = lane >> 4;
  int obase = ot * 256 + wave * 64;
  int lbase = lt * 32;
  const float* xb = x + (size_t)b * C_ * L_;

  {
    int l  = threadIdx.x & 31;
    int cg = threadIdx.x >> 5;         // 0..7
#pragma unroll
    for (int p = 0; p < 16; ++p) {
      int c4 = (p * 8 + cg) * 4;
      float v0 = xb[(size_t)(c4 + 0) * L_ + lbase + l];
      float v1 = xb[(size_t)(c4 + 1) * L_ + lbase + l];
      float v2 = xb[(size_t)(c4 + 2) * L_ + lbase + l];
      float v3 = xb[(size_t)(c4 + 3) * L_ + lbase + l];
      f16x2 p01 = pk2(v0, v1), p23 = pk2(v2, v3);
      f16x4 w = {p01[0], p01[1], p23[0], p23[1]};
      int col = (c4 * 2) ^ ((l & 7) * 16);
      *(f16x4*)(xl + l * 1024 + col) = w;
    }
  }
  __syncthreads();

  f32x4 acc[4][2] = {};
  for (int kc = 0; kc < 512; kc += 32) {
    f16x8 aw[4];
#pragma unroll
    for (int oc = 0; oc < 4; ++oc)
      aw[oc] = *(const f16x8*)(wqkv + (obase + oc * 16 + lo) * 512 + kc + hi * 8);
#pragma unroll
    for (int lc = 0; lc < 2; ++lc) {
      int row = lc * 16 + lo;
      f16x8 bx = *(const f16x8*)(xl + row * 1024 + (((kc + hi * 8) * 2) ^ ((row & 7) * 16)));
#pragma unroll
      for (int oc = 0; oc < 4; ++oc)
        acc[oc][lc] = __builtin_amdgcn_mfma_f32_16x16x32_f16(aw[oc], bx, acc[oc][lc], 0, 0, 0);
    }
  }

  bool is_q = obase < 512;
  int  og   = obase - 512;
  int  kvh  = is_q ? 0 : (og >> 7);
  bool is_v = (!is_q) && ((og & 127) == 64);
  int  h    = obase >> 6;
  const float QSCALE = 0.125f * 1.44269504088896340736f;

#pragma unroll
  for (int oc = 0; oc < 4; ++oc) {
#pragma unroll
    for (int lc = 0; lc < 2; ++lc) {
      f32x4 v = acc[oc][lc];
      int l = lbase + lc * 16 + lo;
      int d = oc * 16 + hi * 4;
      if (!is_v && oc < 2) {           // rotary on d<32 for q and k
        int p0 = d >> 1;
        float2 s0 = sc[l * 16 + p0];
        float2 s1 = sc[l * 16 + p0 + 1];
        float a0 = v[0], a1 = v[1], a2 = v[2], a3 = v[3];
        v[0] = a0 * s0.y - a1 * s0.x;
        v[1] = a1 * s0.y + a0 * s0.x;
        v[2] = a2 * s1.y - a3 * s1.x;
        v[3] = a3 * s1.y + a2 * s1.x;
      }
      if (is_q) {
        f16x4 st = {(f16)(v[0] * QSCALE), (f16)(v[1] * QSCALE),
                    (f16)(v[2] * QSCALE), (f16)(v[3] * QSCALE)};
        *(f16x4*)(Qo + (((size_t)b * 8 + h) * L_ + l) * 64 + d) = st;
      } else if (!is_v) {
        f16x4 st = {(f16)v[0], (f16)v[1], (f16)v[2], (f16)v[3]};
        int t = l >> 6, r = l & 63;
        int u = (d >> 3) ^ (r & 7);
        int w = (hi & 1) * 8;
        char* Kb = (char*)Ko + (size_t)(b * 2 + kvh) * (L_ * 128);
        *(f16x4*)(Kb + (size_t)t * 8192 + r * 128 + u * 16 + w) = st;
      } else {
        int t = l >> 6, kk = l & 63;
        int m = kk >> 3, i8 = kk & 7;
        int ca = (m >> 2) * 64 + ((2 * m) & 3) * 16 + ((m >> 1) & 1) * 8;
        int bcol = ca + (i8 < 4 ? 2 * i8 : 8 + 2 * i8);
        char* Vb = (char*)Vto + (size_t)(b * 2 + kvh) * (L_ * 128);
#pragma unroll
        for (int i = 0; i < 4; ++i) {
          int rv = d + i;
          *(f16*)(Vb + (size_t)t * 8192 + rv * 128 + (bcol ^ ((rv & 7) << 4))) = (f16)v[i];
        }
      }
    }
  }
}

// ---------------------------------------------------------------- flash attention
// Block = 8 waves x 64 q rows = 512 q rows, 512 threads. qi=4. SPLIT=2.
// K/V staged via global_load_lds (linear dest, pre-swizzled source), dbuf.
// COMPUTE restructured for MFMA/VALU overlap: ALL QK MFMAs first (j=0..3),
// then exp/pack(group0)->PV(group0)->exp/pack(group1)->PV(group1) with NO
// setprio fences -- exp(group1) has no dependency on PV(group0), so the
// scheduler can co-issue VALU under the MFMA pipe.
template <int SPLIT>
__global__ __launch_bounds__(512) void attn_kernel(
    const f16* __restrict__ Qi, const f16* __restrict__ Ki,
    const f16* __restrict__ Vti, f16* __restrict__ att,
    f16* __restrict__ opart, float* __restrict__ lsews) {
  __shared__ __align__(16) char smem[2][16384];
  int bid  = blockIdx.x;
  int half = (SPLIT > 1) ? (bid >> 7) : 0;
  int rem7 = bid & 127;
  int b   = rem7 >> 6;
  int rr  = rem7 & 63;
  int h   = rr >> 3;
  int qt  = rr & 7;
  int tid  = threadIdx.x;
  int wave = tid >> 6, lane = tid & 63;
  int lo = lane & 15, hi = lane >> 4;
  int kvh = h >> 2;
  const f16*  Qp   = Qi + ((size_t)(b * 8 + h) * L_) * 64;
  const char* Ksrc = (const char*)Ki  + (size_t)(b * 2 + kvh) * (L_ * 128)
                     + (size_t)half * (L_ / SPLIT) * 128;
  const char* Vsrc = (const char*)Vti + (size_t)(b * 2 + kvh) * (L_ * 128)
                     + (size_t)half * (L_ / SPLIT) * 128;

  int lqb = qt * 512 + wave * 64;
  f16x8 qf[4][2];
#pragma unroll
  for (int qi = 0; qi < 4; ++qi)
#pragma unroll
    for (int hf = 0; hf < 2; ++hf)
      qf[qi][hf] = *(const f16x8*)(Qp + (size_t)(lqb + qi * 16 + lo) * 64 + hf * 32 + hi * 8);

  int c0 = tid;                      // 512 threads x 16B = 8KB tile
#define STAGE(t, base_) do {                                           \
    gl16(Ksrc + (size_t)(t) * 8192 + c0 * 16, (char*)(base_) + c0 * 16); \
    gl16(Vsrc + (size_t)(t) * 8192 + c0 * 16, (char*)(base_) + 8192 + c0 * 16); \
  } while (0)

  f32x4 oacc[4][4] = {};
  f32x4 lse[4] = {};
  const f16x8 ones8 = {(f16)1.f, (f16)1.f, (f16)1.f, (f16)1.f,
                       (f16)1.f, (f16)1.f, (f16)1.f, (f16)1.f};
  int swz = (lo & 7) << 4;

#define COMPUTE(buf_) do {                                                          \
    const char* kb = (const char*)(buf_);                                           \
    const char* vb = kb + 8192;                                                     \
    f32x4 s[4][4] = {};                                                             \
    _Pragma("unroll")                                                               \
    for (int j = 0; j < 4; ++j) {                                                   \
      f16x8 ka0 = *(const f16x8*)(kb + (j * 16 + lo) * 128 + ((hi * 16) ^ swz));    \
      f16x8 ka1 = *(const f16x8*)(kb + (j * 16 + lo) * 128 + ((64 + hi * 16) ^ swz)); \
      _Pragma("unroll")                                                             \
      for (int qi = 0; qi < 4; ++qi) {                                              \
        s[j][qi] = __builtin_amdgcn_mfma_f32_16x16x32_f16(ka0, qf[qi][0], s[j][qi], 0, 0, 0); \
        s[j][qi] = __builtin_amdgcn_mfma_f32_16x16x32_f16(ka1, qf[qi][1], s[j][qi], 0, 0, 0); \
      }                                                                             \
    }                                                                               \
    _Pragma("unroll")                                                               \
    for (int jp = 0; jp < 2; ++jp) {                                                \
      f16x8 pc[4];                                                                  \
      _Pragma("unroll")                                                             \
      for (int qi = 0; qi < 4; ++qi) {                                              \
        f16x2 a0 = pk2(fast_exp2(s[2 * jp][qi][0]), fast_exp2(s[2 * jp][qi][1]));   \
        f16x2 a1 = pk2(fast_exp2(s[2 * jp][qi][2]), fast_exp2(s[2 * jp][qi][3]));   \
        f16x2 b0 = pk2(fast_exp2(s[2 * jp + 1][qi][0]), fast_exp2(s[2 * jp + 1][qi][1])); \
        f16x2 b1 = pk2(fast_exp2(s[2 * jp + 1][qi][2]), fast_exp2(s[2 * jp + 1][qi][3])); \
        f16x4 l4 = __builtin_shufflevector(a0, a1, 0, 1, 2, 3);                     \
        f16x4 h4 = __builtin_shufflevector(b0, b1, 0, 1, 2, 3);                     \
        pc[qi] = __builtin_shufflevector(l4, h4, 0, 1, 2, 3, 4, 5, 6, 7);           \
      }                                                                             \
      _Pragma("unroll")                                                             \
      for (int dc = 0; dc < 4; ++dc) {                                              \
        f16x8 vv = *(const f16x8*)(vb + (dc * 16 + lo) * 128 + ((jp * 64 + hi * 16) ^ swz)); \
        _Pragma("unroll")                                                           \
        for (int qi = 0; qi < 4; ++qi)                                              \
          oacc[dc][qi] = __builtin_amdgcn_mfma_f32_16x16x32_f16(vv, pc[qi], oacc[dc][qi], 0, 0, 0); \
      }                                                                             \
      _Pragma("unroll")                                                             \
      for (int qi = 0; qi < 4; ++qi)                                                \
        lse[qi] = __builtin_amdgcn_mfma_f32_16x16x32_f16(ones8, pc[qi], lse[qi], 0, 0, 0); \
    }                                                                               \
  } while (0)

  const int NT = 64 / SPLIT;
  STAGE(0, smem[0]);
  __syncthreads();

  for (int t = 0; t < NT; ++t) {
    if (t + 1 < NT) STAGE(t + 1, smem[(t + 1) & 1]);
    COMPUTE(smem[t & 1]);
    __syncthreads();
  }

#pragma unroll
  for (int qi = 0; qi < 4; ++qi) {
    int lq = lqb + qi * 16 + lo;
    if constexpr (SPLIT > 1) {
      size_t obase = (((size_t)(half * 2 + b) * 8 + h) * L_ + lq) * 64;
#pragma unroll
      for (int dc = 0; dc < 4; ++dc) {
        f16x4 st;
#pragma unroll
        for (int i = 0; i < 4; ++i) st[i] = (f16)oacc[dc][qi][i];
        *(f16x4*)(opart + obase + dc * 16 + hi * 4) = st;
      }
      if (hi == 0)
        lsews[((size_t)(half * 2 + b) * 8 + h) * L_ + lq] = lse[qi][0];
    } else {
      float inv = 1.f / lse[qi][0];
#pragma unroll
      for (int dc = 0; dc < 4; ++dc) {
        f16x4 st;
#pragma unroll
        for (int i = 0; i < 4; ++i) st[i] = (f16)(oacc[dc][qi][i] * inv);
        *(f16x4*)(att + ((size_t)b * L_ + lq) * 512 + h * 64 + dc * 16 + hi * 4) = st;
      }
    }
  }
#undef STAGE
#undef COMPUTE
}

// ---------------------------------------------------------------- fused combine + output projection (v2)
__global__ __launch_bounds__(256) void oproj_fused_kernel(
    const f16* __restrict__ opart, const float* __restrict__ lsews,
    const f16* __restrict__ wo16, float* __restrict__ out) {
  __shared__ __align__(16) f16 bt[32 * 512];     // [l][o], swizzled
  __shared__ float linv[32][8];
  char* bl = (char*)bt;
  int bid = blockIdx.x;
  int b   = bid >> 7;
  int lt  = bid & 127;
  int lbase = lt * 32;
  int tid  = threadIdx.x;
  int wave = tid >> 6, lane = tid & 63;
  int lo = lane & 15, hi = lane >> 4;
  const size_t HS  = (size_t)2 * 8 * 4096 * 64;   // opart half stride (f16 elems)
  const size_t LSS = (size_t)2 * 8 * 4096;        // lsews half stride

  {
    int r = tid >> 3, h = tid & 7;
    size_t lidx = ((size_t)b * 8 + h) * L_ + lbase + r;
    linv[r][h] = 1.f / (lsews[lidx] + lsews[LSS + lidx]);
  }
  __syncthreads();

#pragma unroll
  for (int p = 0; p < 8; ++p) {
    int idx = p * 256 + tid;
    int r = idx >> 6, u = idx & 63;
    int h = u >> 3, d = (u & 7) * 8;
    size_t base = (((size_t)b * 8 + h) * L_ + lbase + r) * 64 + d;
    f16x8 p0 = *(const f16x8*)(opart + base);
    f16x8 p1 = *(const f16x8*)(opart + HS + base);
    float iv = linv[r][h];
    f16x2 c0 = pk2(((float)p0[0] + (float)p1[0]) * iv, ((float)p0[1] + (float)p1[1]) * iv);
    f16x2 c1 = pk2(((float)p0[2] + (float)p1[2]) * iv, ((float)p0[3] + (float)p1[3]) * iv);
    f16x2 c2 = pk2(((float)p0[4] + (float)p1[4]) * iv, ((float)p0[5] + (float)p1[5]) * iv);
    f16x2 c3 = pk2(((float)p0[6] + (float)p1[6]) * iv, ((float)p0[7] + (float)p1[7]) * iv);
    f16x8 w = {c0[0], c0[1], c1[0], c1[1], c2[0], c2[1], c3[0], c3[1]};
    *(f16x8*)(bl + r * 1024 + ((u * 16) ^ ((r & 7) * 16))) = w;
  }
  __syncthreads();

  float* ob = out + (size_t)b * C_ * L_;
#pragma unroll
  for (int ct = 0; ct < 2; ++ct) {
    int cobase = ct * 256 + wave * 64;
    f32x4 acc[4][2] = {};
    for (int kc = 0; kc < 512; kc += 32) {
      f16x8 aw[4];
#pragma unroll
      for (int cc = 0; cc < 4; ++cc)
        aw[cc] = *(const f16x8*)(wo16 + (cobase + cc * 16 + lo) * 512 + kc + hi * 8);
#pragma unroll
      for (int lc = 0; lc < 2; ++lc) {
        int row = lc * 16 + lo;
        f16x8 bx = *(const f16x8*)(bl + row * 1024 + (((kc + hi * 8) * 2) ^ ((row & 7) * 16)));
#pragma unroll
        for (int cc = 0; cc < 4; ++cc)
          acc[cc][lc] = __builtin_amdgcn_mfma_f32_16x16x32_f16(aw[cc], bx, acc[cc][lc], 0, 0, 0);
      }
    }
#pragma unroll
    for (int cc = 0; cc < 4; ++cc)
#pragma unroll
      for (int lc = 0; lc < 2; ++lc) {
        int l = lbase + lc * 16 + lo;
#pragma unroll
        for (int i = 0; i < 4; ++i) {
          int co = cobase + cc * 16 + hi * 4 + i;
          ob[(size_t)co * L_ + l] = acc[cc][lc][i];
        }
      }
  }
}

// ---------------------------------------------------------------- output projection (SPLIT=1 fallback)
__global__ __launch_bounds__(256) void oproj_kernel(
    const f16* __restrict__ att, const f16* __restrict__ wo16,
    float* __restrict__ out) {
  int bid = blockIdx.x;
  int b   = bid / 256;
  int rem = bid % 256;
  int ct  = rem >> 7;
  int lt  = rem & 127;
  int wave = threadIdx.x >> 6, lane = threadIdx.x & 63;
  int lo = lane & 15, hi = lane >> 4;
  int cobase = ct * 256 + wave * 64;
  int lbase  = lt * 32;
  const f16* ab = att + (size_t)b * L_ * 512;

  f32x4 acc[4][2] = {};
  for (int kc = 0; kc < 512; kc += 32) {
    f16x8 aw[4];
#pragma unroll
    for (int cc = 0; cc < 4; ++cc)
      aw[cc] = *(const f16x8*)(wo16 + (cobase + cc * 16 + lo) * 512 + kc + hi * 8);
#pragma unroll
    for (int lc = 0; lc < 2; ++lc) {
      f16x8 bx = *(const f16x8*)(ab + (size_t)(lbase + lc * 16 + lo) * 512 + kc + hi * 8);
#pragma unroll
      for (int cc = 0; cc < 4; ++cc)
        acc[cc][lc] = __builtin_amdgcn_mfma_f32_16x16x32_f16(aw[cc], bx, acc[cc][lc], 0, 0, 0);
    }
  }
  float* ob = out + (size_t)b * C_ * L_;
#pragma unroll
  for (int cc = 0; cc < 4; ++cc)
#pragma unroll
    for (int lc = 0; lc < 2; ++lc) {
      int l = lbase + lc * 16 + lo;
#pragma unroll
      for (int i = 0; i < 4; ++i) {
        int co = cobase + cc * 16 + hi * 4 + i;
        ob[(size_t)co * L_ + l] = acc[cc][lc][i];
      }
    }
}

// ---------------------------------------------------------------- launch
extern "C" void kernel_launch(void* const* d_in, const int* in_sizes, int n_in,
                              void* d_out, int out_size, void* d_ws, size_t ws_size,
                              hipStream_t stream) {
  const float* x   = (const float*)d_in[0];
  const float* Wq  = (const float*)d_in[1];
  const float* Wkv = (const float*)d_in[2];
  const float* Wo  = (const float*)d_in[3];
  char* ws = (char*)d_ws;
  float2* sc  = (float2*)(ws + WS_SC);
  f16* wqkv   = (f16*)(ws + WS_WQKV);
  f16* wo16   = (f16*)(ws + WS_WO);
  f16* Qb     = (f16*)(ws + WS_Q);
  f16* Kb     = (f16*)(ws + WS_K);
  f16* Vtb    = (f16*)(ws + WS_VT);
  f16* attb   = (f16*)(ws + WS_ATT);
  f16* opb    = (f16*)(ws + WS_OP);
  float* lsb  = (float*)(ws + WS_LS2);

  prep_kernel<<<1024, 256, 0, stream>>>(Wq, Wkv, Wo, wqkv, wo16, sc);
  qkv_kernel<<<768, 256, 0, stream>>>(x, wqkv, sc, Qb, Kb, Vtb);
  if (ws_size >= (size_t)WS_END2) {
    attn_kernel<2><<<256, 512, 0, stream>>>(Qb, Kb, Vtb, attb, opb, lsb);
    oproj_fused_kernel<<<256, 256, 0, stream>>>(opb, lsb, wo16, (float*)d_out);
  } else {
    attn_kernel<1><<<128, 512, 0, stream>>>(Qb, Kb, Vtb, attb, opb, lsb);
    oproj_kernel<<<512, 256, 0, stream>>>(attb, wo16, (float*)d_out);
  }
}